// Round 10
// baseline (155.443 us; speedup 1.0000x reference)
//
#include <hip/hip_runtime.h>

#define N 1024
#define THREADS 256
#define EPT 4  // fallback path

// ---------------------------------------------------------------------------
// Shared pass pipeline (fallback path only, known correct).
// ---------------------------------------------------------------------------
__device__ __forceinline__ float2* run_pipeline(
    float2* bufA, float2* bufB, int tid,
    const float* __restrict__ logits,
    const float* __restrict__ diags,
    const float* __restrict__ subd,
    const float* __restrict__ supd)
{
    float2* src = bufA;
    float2* dst = bufB;

    for (int d = 0; d < 2; ++d) {
        for (int j = 0; j < 9; ++j) {
            const int s = 4 << j;
            const int h = s >> 1;
            const float* lg = logits + (d * 9 + j) * 3;
            const float p0 = 1.0f / (1.0f + expf(-lg[0]));
            const float p1 = 1.0f / (1.0f + expf(-lg[1]));
            const float p2 = 1.0f / (1.0f + expf(-lg[2]));
#pragma unroll
            for (int e = 0; e < EPT; ++e) {
                const int idx = tid + e * THREADS;
                const int base = idx & ~(s - 1);
                const int t = idx & (s - 1);
                const bool lo = (t < h);

                const int eo_t = lo ? (2 * t) : (2 * (t - h) + 1);
                const float2 xt  = src[idx];
                const float2 xeo = src[base + eo_t];
                float2 yt;
                yt.x = xt.x + p0 * (xeo.x - xt.x);
                yt.y = xt.y + p0 * (xeo.y - xt.y);

                const int tm = lo ? (h - 1 - t) : (s + h - 1 - t);
                const float psel = lo ? p1 : p2;
                const int eo_m = (tm < h) ? (2 * tm) : (2 * (tm - h) + 1);
                const float2 xm   = src[base + tm];
                const float2 xmeo = src[base + eo_m];
                float2 ym;
                ym.x = xm.x + p0 * (xmeo.x - xm.x);
                ym.y = xm.y + p0 * (xmeo.y - xm.y);

                float2 o;
                o.x = yt.x + psel * (ym.x - yt.x);
                o.y = yt.y + psel * (ym.y - yt.y);
                dst[idx] = o;
            }
            __syncthreads();
            float2* tmp = src; src = dst; dst = tmp;
        }
        for (int i = 0; i < 10; ++i) {
            const int k = N >> (i + 1);
            const float2* Dg = (const float2*)(diags + (size_t)((d * 10 + i) * N) * 2);
            const float2* Sb = (const float2*)(subd  + (size_t)((d * 10 + i) * N) * 2);
            const float2* Sp = (const float2*)(supd  + (size_t)((d * 10 + i) * N) * 2);
#pragma unroll
            for (int e = 0; e < EPT; ++e) {
                const int idx = tid + e * THREADS;
                const float2 xv = src[idx];
                const float2 dg = Dg[idx];
                float2 o;
                o.x = dg.x * xv.x - dg.y * xv.y;
                o.y = dg.x * xv.y + dg.y * xv.x;
                if (idx >= k) {
                    const float2 xs = src[idx - k];
                    const float2 sb = Sb[idx - k];
                    o.x += sb.x * xs.x - sb.y * xs.y;
                    o.y += sb.x * xs.y + sb.y * xs.x;
                }
                if (idx < N - k) {
                    const float2 xp = src[idx + k];
                    const float2 sp = Sp[idx];
                    o.x += sp.x * xp.x - sp.y * xp.y;
                    o.y += sp.x * xp.y + sp.y * xp.x;
                }
                dst[idx] = o;
            }
            __syncthreads();
            float2* tmp = src; src = dst; dst = tmp;
        }
    }
    return src;
}

// ---------------------------------------------------------------------------
// Fallback: direct per-row kernel (round-1, known correct).
// ---------------------------------------------------------------------------
__global__ __launch_bounds__(THREADS) void trifat_kernel(
    const float* __restrict__ x,
    const float* __restrict__ logits,
    const float* __restrict__ diags,
    const float* __restrict__ subd,
    const float* __restrict__ supd,
    const float* __restrict__ bias,
    float* __restrict__ out,
    int B)
{
    __shared__ float2 bufA[N];
    __shared__ float2 bufB[N];

    const int row = blockIdx.x;
    const int tid = threadIdx.x;
    if (row >= B) return;

    const float* xr = x + (size_t)row * N;
#pragma unroll
    for (int e = 0; e < EPT; ++e) {
        int idx = tid + e * THREADS;
        bufA[idx] = make_float2(xr[idx], 0.0f);
    }
    __syncthreads();

    float2* res = run_pipeline(bufA, bufB, tid, logits, diags, subd, supd);

    float* orow = out + (size_t)row * N;
#pragma unroll
    for (int e = 0; e < EPT; ++e) {
        int idx = tid + e * THREADS;
        orow[idx] = res[idx].x + bias[idx];
    }
}

// ---------------------------------------------------------------------------
// bf16 helper
// ---------------------------------------------------------------------------
__device__ __forceinline__ unsigned short f2bf_rne(float f) {
    unsigned int u = __float_as_uint(f);
    unsigned int r = u + 0x7fffu + ((u >> 16) & 1u);
    return (unsigned short)(r >> 16);
}

// ---------------------------------------------------------------------------
// Fused prep kernel, 1024 threads/block:
//  blocks [0,512):   build two basis-vector images (V=2, 32 KB LDS,
//                    mirror-pair perms, shared coefficients) -> scatter Bt.
//                    2 blocks/CU x 16 waves = 32 waves/CU (100% occupancy),
//                    vs round-9's 16 waves/CU: TLP is the measured limiter
//                    (VALUBusy 38%, Occupancy 38%).
//  blocks [512,768): conv x -> A2 bf16, 16384 floats/block.
// ---------------------------------------------------------------------------
#define TBW 1024
#define NB_BUILD 512

__global__ __launch_bounds__(TBW, 8) void prep_kernel(
    const float* __restrict__ logits,
    const float* __restrict__ diags,
    const float* __restrict__ subd,
    const float* __restrict__ supd,
    const float* __restrict__ x,
    unsigned short* __restrict__ Bt,   // [1024][1024] bf16, Bt[n][j]
    unsigned short* __restrict__ A2)   // [B][1024] bf16
{
    __shared__ float2 buf[2][2][N];  // [buffer][vector][pos], 32 KB

    const int tid = threadIdx.x;

    if (blockIdx.x >= NB_BUILD) {
        // ---------------- conv role ----------------
        const int cb = blockIdx.x - NB_BUILD;        // 0..255
        const size_t base4 = (size_t)cb * 4096;      // float4 index base
#pragma unroll
        for (int r = 0; r < 4; ++r) {
            const size_t g4 = base4 + r * 1024 + tid;
            const float4 v = *(const float4*)(x + g4 * 4);
            ushort4 o;
            o.x = f2bf_rne(v.x);
            o.y = f2bf_rne(v.y);
            o.z = f2bf_rne(v.z);
            o.w = f2bf_rne(v.w);
            *(ushort4*)(A2 + g4 * 4) = o;
        }
        return;
    }

    // ---------------- build role ----------------
    const int j0 = blockIdx.x * 2;

#pragma unroll
    for (int v = 0; v < 2; ++v)
        buf[0][v][tid] = make_float2(tid == (j0 + v) ? 1.0f : 0.0f, 0.0f);
    __syncthreads();

    int sb = 0;
    for (int d = 0; d < 2; ++d) {
        // ---- 9 perm passes, mirror-pair formulation (1024 pair-tasks) ----
        for (int jp = 0; jp < 9; ++jp) {
            const int s = 4 << jp;
            const int h = s >> 1;
            const int hh = s >> 2;
            const float* lg = logits + (d * 9 + jp) * 3;
            const float p0 = 1.0f / (1.0f + expf(-lg[0]));
            const float p1 = 1.0f / (1.0f + expf(-lg[1]));
            const float p2 = 1.0f / (1.0f + expf(-lg[2]));
            {
                const int tau = tid;                   // 0..1023
                const int v = tau >> 9;
                const int pid = tau & 511;             // pair id within vector
                const int w = pid & ((s >> 1) - 1);    // pair within s-block
                const int base = (pid >> (jp + 1)) << (jp + 2);

                int t, tm;
                float psel;
                if (w < hh) { t = w;          tm = h - 1 - w;  psel = p1; }
                else        { const int u = w - hh; t = h + u; tm = s - 1 - u; psel = p2; }

                const int eot = (t  < h) ? (2 * t)  : (2 * (t  - h) + 1);
                const int eom = (tm < h) ? (2 * tm) : (2 * (tm - h) + 1);

                const float2* src = buf[sb][v];
                float2* dst = buf[sb ^ 1][v];

                const float2 xt = src[base + t],  xet = src[base + eot];
                const float2 xm = src[base + tm], xem = src[base + eom];
                float2 yt, ym;
                yt.x = xt.x + p0 * (xet.x - xt.x);
                yt.y = xt.y + p0 * (xet.y - xt.y);
                ym.x = xm.x + p0 * (xem.x - xm.x);
                ym.y = xm.y + p0 * (xem.y - xm.y);

                float2 ot, om;
                ot.x = yt.x + psel * (ym.x - yt.x);
                ot.y = yt.y + psel * (ym.y - yt.y);
                om.x = ym.x + psel * (yt.x - ym.x);
                om.y = ym.y + psel * (yt.y - ym.y);
                dst[base + t]  = ot;
                dst[base + tm] = om;
            }
            __syncthreads();
            sb ^= 1;
        }
        // ---- 10 butterfly passes, coefficients shared across both vectors ----
        for (int i = 0; i < 10; ++i) {
            const int k = N >> (i + 1);
            const float2* Dg  = (const float2*)(diags + (size_t)((d * 10 + i) * N) * 2);
            const float2* Sbc = (const float2*)(subd  + (size_t)((d * 10 + i) * N) * 2);
            const float2* Spc = (const float2*)(supd  + (size_t)((d * 10 + i) * N) * 2);
            {
                const int idx = tid;
                const float2 dg = Dg[idx];
                float2 sbv = make_float2(0.f, 0.f), spv = make_float2(0.f, 0.f);
                if (idx >= k)     sbv = Sbc[idx - k];
                if (idx < N - k)  spv = Spc[idx];
#pragma unroll
                for (int v = 0; v < 2; ++v) {
                    const float2* src = buf[sb][v];
                    const float2 xv = src[idx];
                    float2 o;
                    o.x = dg.x * xv.x - dg.y * xv.y;
                    o.y = dg.x * xv.y + dg.y * xv.x;
                    if (idx >= k) {
                        const float2 xs = src[idx - k];
                        o.x += sbv.x * xs.x - sbv.y * xs.y;
                        o.y += sbv.x * xs.y + sbv.y * xs.x;
                    }
                    if (idx < N - k) {
                        const float2 xp = src[idx + k];
                        o.x += spv.x * xp.x - spv.y * xp.y;
                        o.y += spv.x * xp.y + spv.y * xp.x;
                    }
                    buf[sb ^ 1][v][idx] = o;
                }
            }
            __syncthreads();
            sb ^= 1;
        }
    }

    // ---- epilogue: scatter-write transposed bf16 directly: Bt[n][j0+v] ----
#pragma unroll
    for (int v = 0; v < 2; ++v)
        Bt[(size_t)tid * N + (j0 + v)] = f2bf_rne(buf[sb][v][tid].x);
}

// ---------------------------------------------------------------------------
// GEMM: BM=64 x BN=64 tile, BK=64, grid (64,16)=1024 blocks -> 4 blocks/CU.
// m97-style 2-barrier single-buffer K-loop; XOR-swizzled LDS; unchanged
// from round 9 (known good).
// ---------------------------------------------------------------------------
typedef __attribute__((ext_vector_type(8))) __bf16 bf16x8;
typedef __attribute__((ext_vector_type(4))) float f32x4;

#define GLB(p) ((const __attribute__((address_space(1))) void*)(p))
#define LDS(p) ((__attribute__((address_space(3))) void*)(p))

__global__ __launch_bounds__(THREADS) void gemm_bf16(
    const unsigned short* __restrict__ A2,  // [B][1024] bf16
    const unsigned short* __restrict__ Bt,  // [1024][1024] bf16
    const float* __restrict__ bias,
    float* __restrict__ out)
{
    __shared__ __align__(16) unsigned short As[64 * 64];    // 8 KB
    __shared__ __align__(16) unsigned short Bs[64 * 64];    // 8 KB

    const int m0 = blockIdx.x * 64;
    const int n0 = blockIdx.y * 64;
    const int tid = threadIdx.x;
    const int wave = tid >> 6, lane = tid & 63;
    const int wm = (wave >> 1) * 32, wn = (wave & 1) * 32;
    const int lrow = lane & 15, q = lane >> 4;
    const int r7 = lrow & 7;

    f32x4 acc[2][2] = {};

    for (int kt = 0; kt < 16; ++kt) {
        const int k0 = kt * 64;
        __syncthreads();  // previous tile fully consumed
        {
            const unsigned short* gA = A2 + (size_t)m0 * N + k0;
            const unsigned short* gB = Bt + (size_t)n0 * N + k0;
#pragma unroll
            for (int r = 0; r < 2; ++r) {
                const int s = r * 256 + tid;
                const int row = s >> 3;
                const int gl = (s & 7) ^ (row & 7);  // XOR-swizzled k-group
                __builtin_amdgcn_global_load_lds(GLB(gA + (size_t)row * N + gl * 8),
                                                 LDS(As + s * 8), 16, 0, 0);
                __builtin_amdgcn_global_load_lds(GLB(gB + (size_t)row * N + gl * 8),
                                                 LDS(Bs + s * 8), 16, 0, 0);
            }
        }
        __syncthreads();  // DMA drained -> tile ready

#pragma unroll
        for (int kk = 0; kk < 64; kk += 32) {
            const int pg = ((kk >> 3) + q) ^ r7;  // physical (swizzled) group
            bf16x8 a[2], b[2];
#pragma unroll
            for (int mi = 0; mi < 2; ++mi)
                a[mi] = *(const bf16x8*)(As + (wm + mi * 16 + lrow) * 64 + pg * 8);
#pragma unroll
            for (int ni = 0; ni < 2; ++ni)
                b[ni] = *(const bf16x8*)(Bs + (wn + ni * 16 + lrow) * 64 + pg * 8);
#pragma unroll
            for (int mi = 0; mi < 2; ++mi)
#pragma unroll
                for (int ni = 0; ni < 2; ++ni)
                    acc[mi][ni] = __builtin_amdgcn_mfma_f32_16x16x32_bf16(
                        a[mi], b[ni], acc[mi][ni], 0, 0, 0);
        }
    }

    // epilogue: C/D layout col=lane&15, row=q*4+reg
#pragma unroll
    for (int ni = 0; ni < 2; ++ni) {
        const int col = n0 + wn + ni * 16 + lrow;
        const float bv = bias[col];
#pragma unroll
        for (int mi = 0; mi < 2; ++mi)
#pragma unroll
            for (int r = 0; r < 4; ++r) {
                const int row = m0 + wm + mi * 16 + q * 4 + r;
                out[(size_t)row * N + col] = acc[mi][ni][r] + bv;
            }
    }
}

// ---------------------------------------------------------------------------
extern "C" void kernel_launch(void* const* d_in, const int* in_sizes, int n_in,
                              void* d_out, int out_size, void* d_ws, size_t ws_size,
                              hipStream_t stream) {
    const float* x      = (const float*)d_in[0];
    const float* logits = (const float*)d_in[1];
    const float* diags  = (const float*)d_in[2];
    const float* subd   = (const float*)d_in[3];
    const float* supd   = (const float*)d_in[4];
    const float* bias   = (const float*)d_in[5];
    float* out = (float*)d_out;

    const int B = in_sizes[0] / N;  // 4096

    const size_t off_Bt = 0;                                // Bt: 1024*1024*2 B
    const size_t off_A2 = 2u * 1024 * 1024;
    const size_t need   = off_A2 + (size_t)B * N * 2;       // A2: B*1024*2 B

    if (ws_size >= need && B == 4096) {
        unsigned short* Bt = (unsigned short*)((char*)d_ws + off_Bt);
        unsigned short* A2 = (unsigned short*)((char*)d_ws + off_A2);

        prep_kernel<<<dim3(NB_BUILD + 256), dim3(TBW), 0, stream>>>(
            logits, diags, subd, supd, x, Bt, A2);
        gemm_bf16<<<dim3(B / 64, 16), dim3(THREADS), 0, stream>>>(A2, Bt, bias, out);
    } else {
        trifat_kernel<<<dim3(B), dim3(THREADS), 0, stream>>>(
            x, logits, diags, subd, supd, bias, out, B);
    }
}

// Round 11
// 139.868 us; speedup vs baseline: 1.1114x; 1.1114x over previous
//
#include <hip/hip_runtime.h>

#define N 1024
#define THREADS 256
#define EPT 4  // fallback path

// ---------------------------------------------------------------------------
// Shared pass pipeline (fallback path only, known correct).
// ---------------------------------------------------------------------------
__device__ __forceinline__ float2* run_pipeline(
    float2* bufA, float2* bufB, int tid,
    const float* __restrict__ logits,
    const float* __restrict__ diags,
    const float* __restrict__ subd,
    const float* __restrict__ supd)
{
    float2* src = bufA;
    float2* dst = bufB;

    for (int d = 0; d < 2; ++d) {
        for (int j = 0; j < 9; ++j) {
            const int s = 4 << j;
            const int h = s >> 1;
            const float* lg = logits + (d * 9 + j) * 3;
            const float p0 = 1.0f / (1.0f + expf(-lg[0]));
            const float p1 = 1.0f / (1.0f + expf(-lg[1]));
            const float p2 = 1.0f / (1.0f + expf(-lg[2]));
#pragma unroll
            for (int e = 0; e < EPT; ++e) {
                const int idx = tid + e * THREADS;
                const int base = idx & ~(s - 1);
                const int t = idx & (s - 1);
                const bool lo = (t < h);

                const int eo_t = lo ? (2 * t) : (2 * (t - h) + 1);
                const float2 xt  = src[idx];
                const float2 xeo = src[base + eo_t];
                float2 yt;
                yt.x = xt.x + p0 * (xeo.x - xt.x);
                yt.y = xt.y + p0 * (xeo.y - xt.y);

                const int tm = lo ? (h - 1 - t) : (s + h - 1 - t);
                const float psel = lo ? p1 : p2;
                const int eo_m = (tm < h) ? (2 * tm) : (2 * (tm - h) + 1);
                const float2 xm   = src[base + tm];
                const float2 xmeo = src[base + eo_m];
                float2 ym;
                ym.x = xm.x + p0 * (xmeo.x - xm.x);
                ym.y = xm.y + p0 * (xmeo.y - xm.y);

                float2 o;
                o.x = yt.x + psel * (ym.x - yt.x);
                o.y = yt.y + psel * (ym.y - yt.y);
                dst[idx] = o;
            }
            __syncthreads();
            float2* tmp = src; src = dst; dst = tmp;
        }
        for (int i = 0; i < 10; ++i) {
            const int k = N >> (i + 1);
            const float2* Dg = (const float2*)(diags + (size_t)((d * 10 + i) * N) * 2);
            const float2* Sb = (const float2*)(subd  + (size_t)((d * 10 + i) * N) * 2);
            const float2* Sp = (const float2*)(supd  + (size_t)((d * 10 + i) * N) * 2);
#pragma unroll
            for (int e = 0; e < EPT; ++e) {
                const int idx = tid + e * THREADS;
                const float2 xv = src[idx];
                const float2 dg = Dg[idx];
                float2 o;
                o.x = dg.x * xv.x - dg.y * xv.y;
                o.y = dg.x * xv.y + dg.y * xv.x;
                if (idx >= k) {
                    const float2 xs = src[idx - k];
                    const float2 sb = Sb[idx - k];
                    o.x += sb.x * xs.x - sb.y * xs.y;
                    o.y += sb.x * xs.y + sb.y * xs.x;
                }
                if (idx < N - k) {
                    const float2 xp = src[idx + k];
                    const float2 sp = Sp[idx];
                    o.x += sp.x * xp.x - sp.y * xp.y;
                    o.y += sp.x * xp.y + sp.y * xp.x;
                }
                dst[idx] = o;
            }
            __syncthreads();
            float2* tmp = src; src = dst; dst = tmp;
        }
    }
    return src;
}

// ---------------------------------------------------------------------------
// Fallback: direct per-row kernel (round-1, known correct).
// ---------------------------------------------------------------------------
__global__ __launch_bounds__(THREADS) void trifat_kernel(
    const float* __restrict__ x,
    const float* __restrict__ logits,
    const float* __restrict__ diags,
    const float* __restrict__ subd,
    const float* __restrict__ supd,
    const float* __restrict__ bias,
    float* __restrict__ out,
    int B)
{
    __shared__ float2 bufA[N];
    __shared__ float2 bufB[N];

    const int row = blockIdx.x;
    const int tid = threadIdx.x;
    if (row >= B) return;

    const float* xr = x + (size_t)row * N;
#pragma unroll
    for (int e = 0; e < EPT; ++e) {
        int idx = tid + e * THREADS;
        bufA[idx] = make_float2(xr[idx], 0.0f);
    }
    __syncthreads();

    float2* res = run_pipeline(bufA, bufB, tid, logits, diags, subd, supd);

    float* orow = out + (size_t)row * N;
#pragma unroll
    for (int e = 0; e < EPT; ++e) {
        int idx = tid + e * THREADS;
        orow[idx] = res[idx].x + bias[idx];
    }
}

// ---------------------------------------------------------------------------
// bf16 helper
// ---------------------------------------------------------------------------
__device__ __forceinline__ unsigned short f2bf_rne(float f) {
    unsigned int u = __float_as_uint(f);
    unsigned int r = u + 0x7fffu + ((u >> 16) & 1u);
    return (unsigned short)(r >> 16);
}

// ---------------------------------------------------------------------------
// Fused prep kernel, 512 threads/block (r9 occupancy shape: 16 waves/CU),
// V=4 basis vectors per block (64 KB LDS, 2 blocks/CU):
//   - 2x ILP per thread vs r9 (8 indep LDS chains per butterfly pass)
//   - coefficients amortized over 4 vectors; global fetch halves
//  blocks [0,256):   build 4 basis-vector images -> scatter Bt bf16
//  blocks [256,512): conv x -> A2 bf16
// ---------------------------------------------------------------------------
#define TBW 512
#define NB_BUILD 256
#define VPB 4

__global__ __launch_bounds__(TBW) void prep_kernel(
    const float* __restrict__ logits,
    const float* __restrict__ diags,
    const float* __restrict__ subd,
    const float* __restrict__ supd,
    const float* __restrict__ x,
    unsigned short* __restrict__ Bt,   // [1024][1024] bf16, Bt[n][j]
    unsigned short* __restrict__ A2)   // [B][1024] bf16
{
    __shared__ float2 buf[2][VPB][N];  // [buffer][vector][pos], 64 KB

    const int tid = threadIdx.x;

    if (blockIdx.x >= NB_BUILD) {
        // ---------------- conv role ----------------
        const int cb = blockIdx.x - NB_BUILD;        // 0..255
        const size_t base4 = (size_t)cb * 4096;      // float4 index base
#pragma unroll
        for (int r = 0; r < 8; ++r) {
            const size_t g4 = base4 + r * 512 + tid;
            const float4 v = *(const float4*)(x + g4 * 4);
            ushort4 o;
            o.x = f2bf_rne(v.x);
            o.y = f2bf_rne(v.y);
            o.z = f2bf_rne(v.z);
            o.w = f2bf_rne(v.w);
            *(ushort4*)(A2 + g4 * 4) = o;
        }
        return;
    }

    // ---------------- build role ----------------
    const int j0 = blockIdx.x * VPB;

#pragma unroll
    for (int v = 0; v < VPB; ++v)
#pragma unroll
        for (int e = 0; e < 2; ++e) {
            const int idx = tid + e * TBW;
            buf[0][v][idx] = make_float2(idx == (j0 + v) ? 1.0f : 0.0f, 0.0f);
        }
    __syncthreads();

    int sb = 0;
    for (int d = 0; d < 2; ++d) {
        // ---- 9 perm passes, mirror-pair formulation (2048 pair-tasks) ----
        for (int jp = 0; jp < 9; ++jp) {
            const int s = 4 << jp;
            const int h = s >> 1;
            const int hh = s >> 2;
            const float* lg = logits + (d * 9 + jp) * 3;
            const float p0 = 1.0f / (1.0f + expf(-lg[0]));
            const float p1 = 1.0f / (1.0f + expf(-lg[1]));
            const float p2 = 1.0f / (1.0f + expf(-lg[2]));
#pragma unroll
            for (int e = 0; e < VPB; ++e) {
                const int tau = tid + e * TBW;         // 0..2047
                const int v = tau >> 9;                // 0..3
                const int pid = tau & 511;             // pair id within vector
                const int w = pid & ((s >> 1) - 1);    // pair within s-block
                const int base = (pid >> (jp + 1)) << (jp + 2);

                int t, tm;
                float psel;
                if (w < hh) { t = w;          tm = h - 1 - w;  psel = p1; }
                else        { const int u = w - hh; t = h + u; tm = s - 1 - u; psel = p2; }

                const int eot = (t  < h) ? (2 * t)  : (2 * (t  - h) + 1);
                const int eom = (tm < h) ? (2 * tm) : (2 * (tm - h) + 1);

                const float2* src = buf[sb][v];
                float2* dst = buf[sb ^ 1][v];

                const float2 xt = src[base + t],  xet = src[base + eot];
                const float2 xm = src[base + tm], xem = src[base + eom];
                float2 yt, ym;
                yt.x = xt.x + p0 * (xet.x - xt.x);
                yt.y = xt.y + p0 * (xet.y - xt.y);
                ym.x = xm.x + p0 * (xem.x - xm.x);
                ym.y = xm.y + p0 * (xem.y - xm.y);

                float2 ot, om;
                ot.x = yt.x + psel * (ym.x - yt.x);
                ot.y = yt.y + psel * (ym.y - yt.y);
                om.x = ym.x + psel * (yt.x - ym.x);
                om.y = ym.y + psel * (yt.y - ym.y);
                dst[base + t]  = ot;
                dst[base + tm] = om;
            }
            __syncthreads();
            sb ^= 1;
        }
        // ---- 10 butterfly passes, coefficients shared across 4 vectors ----
        for (int i = 0; i < 10; ++i) {
            const int k = N >> (i + 1);
            const float2* Dg  = (const float2*)(diags + (size_t)((d * 10 + i) * N) * 2);
            const float2* Sbc = (const float2*)(subd  + (size_t)((d * 10 + i) * N) * 2);
            const float2* Spc = (const float2*)(supd  + (size_t)((d * 10 + i) * N) * 2);
#pragma unroll
            for (int e = 0; e < 2; ++e) {
                const int idx = tid + e * TBW;
                const float2 dg = Dg[idx];
                float2 sbv = make_float2(0.f, 0.f), spv = make_float2(0.f, 0.f);
                if (idx >= k)     sbv = Sbc[idx - k];
                if (idx < N - k)  spv = Spc[idx];
#pragma unroll
                for (int v = 0; v < VPB; ++v) {
                    const float2* src = buf[sb][v];
                    const float2 xv = src[idx];
                    float2 o;
                    o.x = dg.x * xv.x - dg.y * xv.y;
                    o.y = dg.x * xv.y + dg.y * xv.x;
                    if (idx >= k) {
                        const float2 xs = src[idx - k];
                        o.x += sbv.x * xs.x - sbv.y * xs.y;
                        o.y += sbv.x * xs.y + sbv.y * xs.x;
                    }
                    if (idx < N - k) {
                        const float2 xp = src[idx + k];
                        o.x += spv.x * xp.x - spv.y * xp.y;
                        o.y += spv.x * xp.y + spv.y * xp.x;
                    }
                    buf[sb ^ 1][v][idx] = o;
                }
            }
            __syncthreads();
            sb ^= 1;
        }
    }

    // ---- epilogue: scatter-write transposed bf16 directly: Bt[n][j0+v] ----
#pragma unroll
    for (int v = 0; v < VPB; ++v)
#pragma unroll
        for (int e = 0; e < 2; ++e) {
            const int idx = tid + e * TBW;
            Bt[(size_t)idx * N + (j0 + v)] = f2bf_rne(buf[sb][v][idx].x);
        }
}

// ---------------------------------------------------------------------------
// GEMM: BM=64 x BN=64 tile, BK=64, grid (64,16)=1024 blocks -> 4 blocks/CU.
// m97-style 2-barrier single-buffer K-loop; XOR-swizzled LDS; unchanged
// from round 9 (known good).
// ---------------------------------------------------------------------------
typedef __attribute__((ext_vector_type(8))) __bf16 bf16x8;
typedef __attribute__((ext_vector_type(4))) float f32x4;

#define GLB(p) ((const __attribute__((address_space(1))) void*)(p))
#define LDS(p) ((__attribute__((address_space(3))) void*)(p))

__global__ __launch_bounds__(THREADS) void gemm_bf16(
    const unsigned short* __restrict__ A2,  // [B][1024] bf16
    const unsigned short* __restrict__ Bt,  // [1024][1024] bf16
    const float* __restrict__ bias,
    float* __restrict__ out)
{
    __shared__ __align__(16) unsigned short As[64 * 64];    // 8 KB
    __shared__ __align__(16) unsigned short Bs[64 * 64];    // 8 KB

    const int m0 = blockIdx.x * 64;
    const int n0 = blockIdx.y * 64;
    const int tid = threadIdx.x;
    const int wave = tid >> 6, lane = tid & 63;
    const int wm = (wave >> 1) * 32, wn = (wave & 1) * 32;
    const int lrow = lane & 15, q = lane >> 4;
    const int r7 = lrow & 7;

    f32x4 acc[2][2] = {};

    for (int kt = 0; kt < 16; ++kt) {
        const int k0 = kt * 64;
        __syncthreads();  // previous tile fully consumed
        {
            const unsigned short* gA = A2 + (size_t)m0 * N + k0;
            const unsigned short* gB = Bt + (size_t)n0 * N + k0;
#pragma unroll
            for (int r = 0; r < 2; ++r) {
                const int s = r * 256 + tid;
                const int row = s >> 3;
                const int gl = (s & 7) ^ (row & 7);  // XOR-swizzled k-group
                __builtin_amdgcn_global_load_lds(GLB(gA + (size_t)row * N + gl * 8),
                                                 LDS(As + s * 8), 16, 0, 0);
                __builtin_amdgcn_global_load_lds(GLB(gB + (size_t)row * N + gl * 8),
                                                 LDS(Bs + s * 8), 16, 0, 0);
            }
        }
        __syncthreads();  // DMA drained -> tile ready

#pragma unroll
        for (int kk = 0; kk < 64; kk += 32) {
            const int pg = ((kk >> 3) + q) ^ r7;  // physical (swizzled) group
            bf16x8 a[2], b[2];
#pragma unroll
            for (int mi = 0; mi < 2; ++mi)
                a[mi] = *(const bf16x8*)(As + (wm + mi * 16 + lrow) * 64 + pg * 8);
#pragma unroll
            for (int ni = 0; ni < 2; ++ni)
                b[ni] = *(const bf16x8*)(Bs + (wn + ni * 16 + lrow) * 64 + pg * 8);
#pragma unroll
            for (int mi = 0; mi < 2; ++mi)
#pragma unroll
                for (int ni = 0; ni < 2; ++ni)
                    acc[mi][ni] = __builtin_amdgcn_mfma_f32_16x16x32_bf16(
                        a[mi], b[ni], acc[mi][ni], 0, 0, 0);
        }
    }

    // epilogue: C/D layout col=lane&15, row=q*4+reg
#pragma unroll
    for (int ni = 0; ni < 2; ++ni) {
        const int col = n0 + wn + ni * 16 + lrow;
        const float bv = bias[col];
#pragma unroll
        for (int mi = 0; mi < 2; ++mi)
#pragma unroll
            for (int r = 0; r < 4; ++r) {
                const int row = m0 + wm + mi * 16 + q * 4 + r;
                out[(size_t)row * N + col] = acc[mi][ni][r] + bv;
            }
    }
}

// ---------------------------------------------------------------------------
extern "C" void kernel_launch(void* const* d_in, const int* in_sizes, int n_in,
                              void* d_out, int out_size, void* d_ws, size_t ws_size,
                              hipStream_t stream) {
    const float* x      = (const float*)d_in[0];
    const float* logits = (const float*)d_in[1];
    const float* diags  = (const float*)d_in[2];
    const float* subd   = (const float*)d_in[3];
    const float* supd   = (const float*)d_in[4];
    const float* bias   = (const float*)d_in[5];
    float* out = (float*)d_out;

    const int B = in_sizes[0] / N;  // 4096

    const size_t off_Bt = 0;                                // Bt: 1024*1024*2 B
    const size_t off_A2 = 2u * 1024 * 1024;
    const size_t need   = off_A2 + (size_t)B * N * 2;       // A2: B*1024*2 B

    if (ws_size >= need && B == 4096) {
        unsigned short* Bt = (unsigned short*)((char*)d_ws + off_Bt);
        unsigned short* A2 = (unsigned short*)((char*)d_ws + off_A2);

        prep_kernel<<<dim3(NB_BUILD + 256), dim3(TBW), 0, stream>>>(
            logits, diags, subd, supd, x, Bt, A2);
        gemm_bf16<<<dim3(B / 64, 16), dim3(THREADS), 0, stream>>>(A2, Bt, bias, out);
    } else {
        trifat_kernel<<<dim3(B), dim3(THREADS), 0, stream>>>(
            x, logits, diags, subd, supd, bias, out, B);
    }
}

// Round 12
// 129.639 us; speedup vs baseline: 1.1991x; 1.0789x over previous
//
#include <hip/hip_runtime.h>

#define N 1024
#define THREADS 256
#define EPT 4  // fallback path

// ---------------------------------------------------------------------------
// Shared pass pipeline (fallback path only, known correct).
// ---------------------------------------------------------------------------
__device__ __forceinline__ float2* run_pipeline(
    float2* bufA, float2* bufB, int tid,
    const float* __restrict__ logits,
    const float* __restrict__ diags,
    const float* __restrict__ subd,
    const float* __restrict__ supd)
{
    float2* src = bufA;
    float2* dst = bufB;

    for (int d = 0; d < 2; ++d) {
        for (int j = 0; j < 9; ++j) {
            const int s = 4 << j;
            const int h = s >> 1;
            const float* lg = logits + (d * 9 + j) * 3;
            const float p0 = 1.0f / (1.0f + expf(-lg[0]));
            const float p1 = 1.0f / (1.0f + expf(-lg[1]));
            const float p2 = 1.0f / (1.0f + expf(-lg[2]));
#pragma unroll
            for (int e = 0; e < EPT; ++e) {
                const int idx = tid + e * THREADS;
                const int base = idx & ~(s - 1);
                const int t = idx & (s - 1);
                const bool lo = (t < h);

                const int eo_t = lo ? (2 * t) : (2 * (t - h) + 1);
                const float2 xt  = src[idx];
                const float2 xeo = src[base + eo_t];
                float2 yt;
                yt.x = xt.x + p0 * (xeo.x - xt.x);
                yt.y = xt.y + p0 * (xeo.y - xt.y);

                const int tm = lo ? (h - 1 - t) : (s + h - 1 - t);
                const float psel = lo ? p1 : p2;
                const int eo_m = (tm < h) ? (2 * tm) : (2 * (tm - h) + 1);
                const float2 xm   = src[base + tm];
                const float2 xmeo = src[base + eo_m];
                float2 ym;
                ym.x = xm.x + p0 * (xmeo.x - xm.x);
                ym.y = xm.y + p0 * (xmeo.y - xm.y);

                float2 o;
                o.x = yt.x + psel * (ym.x - yt.x);
                o.y = yt.y + psel * (ym.y - yt.y);
                dst[idx] = o;
            }
            __syncthreads();
            float2* tmp = src; src = dst; dst = tmp;
        }
        for (int i = 0; i < 10; ++i) {
            const int k = N >> (i + 1);
            const float2* Dg = (const float2*)(diags + (size_t)((d * 10 + i) * N) * 2);
            const float2* Sb = (const float2*)(subd  + (size_t)((d * 10 + i) * N) * 2);
            const float2* Sp = (const float2*)(supd  + (size_t)((d * 10 + i) * N) * 2);
#pragma unroll
            for (int e = 0; e < EPT; ++e) {
                const int idx = tid + e * THREADS;
                const float2 xv = src[idx];
                const float2 dg = Dg[idx];
                float2 o;
                o.x = dg.x * xv.x - dg.y * xv.y;
                o.y = dg.x * xv.y + dg.y * xv.x;
                if (idx >= k) {
                    const float2 xs = src[idx - k];
                    const float2 sb = Sb[idx - k];
                    o.x += sb.x * xs.x - sb.y * xs.y;
                    o.y += sb.x * xs.y + sb.y * xs.x;
                }
                if (idx < N - k) {
                    const float2 xp = src[idx + k];
                    const float2 sp = Sp[idx];
                    o.x += sp.x * xp.x - sp.y * xp.y;
                    o.y += sp.x * xp.y + sp.y * xp.x;
                }
                dst[idx] = o;
            }
            __syncthreads();
            float2* tmp = src; src = dst; dst = tmp;
        }
    }
    return src;
}

// ---------------------------------------------------------------------------
// Fallback: direct per-row kernel (round-1, known correct).
// ---------------------------------------------------------------------------
__global__ __launch_bounds__(THREADS) void trifat_kernel(
    const float* __restrict__ x,
    const float* __restrict__ logits,
    const float* __restrict__ diags,
    const float* __restrict__ subd,
    const float* __restrict__ supd,
    const float* __restrict__ bias,
    float* __restrict__ out,
    int B)
{
    __shared__ float2 bufA[N];
    __shared__ float2 bufB[N];

    const int row = blockIdx.x;
    const int tid = threadIdx.x;
    if (row >= B) return;

    const float* xr = x + (size_t)row * N;
#pragma unroll
    for (int e = 0; e < EPT; ++e) {
        int idx = tid + e * THREADS;
        bufA[idx] = make_float2(xr[idx], 0.0f);
    }
    __syncthreads();

    float2* res = run_pipeline(bufA, bufB, tid, logits, diags, subd, supd);

    float* orow = out + (size_t)row * N;
#pragma unroll
    for (int e = 0; e < EPT; ++e) {
        int idx = tid + e * THREADS;
        orow[idx] = res[idx].x + bias[idx];
    }
}

// ---------------------------------------------------------------------------
// bf16 helper
// ---------------------------------------------------------------------------
__device__ __forceinline__ unsigned short f2bf_rne(float f) {
    unsigned int u = __float_as_uint(f);
    unsigned int r = u + 0x7fffu + ((u >> 16) & 1u);
    return (unsigned short)(r >> 16);
}

// ---------------------------------------------------------------------------
// Fused prep kernel — r9 shape (TBW=512, V=2, 32 KB LDS, 16 waves/CU) plus:
//   * software prefetch: butterfly pass i+1's coefficients (dg/sub/sup) are
//     loaded into registers BEFORE pass i's LDS reads, hiding ~200-400 cyc
//     of L2 latency per pass behind the pass's own compute + barrier;
//   * perm passes: with V=2/TBW=512 both vectors share the same pair id, so
//     index math is computed once and applied to both vectors.
//  blocks [0,512):   build 2 basis-vector images -> scatter Bt bf16
//  blocks [512,768): conv x -> A2 bf16
// ---------------------------------------------------------------------------
#define TBW 512
#define NB_BUILD 512

__global__ __launch_bounds__(TBW) void prep_kernel(
    const float* __restrict__ logits,
    const float* __restrict__ diags,
    const float* __restrict__ subd,
    const float* __restrict__ supd,
    const float* __restrict__ x,
    unsigned short* __restrict__ Bt,   // [1024][1024] bf16, Bt[n][j]
    unsigned short* __restrict__ A2)   // [B][1024] bf16
{
    __shared__ float2 buf[2][2][N];  // [buffer][vector][pos], 32 KB

    const int tid = threadIdx.x;

    if (blockIdx.x >= NB_BUILD) {
        // ---------------- conv role ----------------
        const int cb = blockIdx.x - NB_BUILD;        // 0..255
        const size_t base4 = (size_t)cb * 4096;      // float4 index base
#pragma unroll
        for (int r = 0; r < 8; ++r) {
            const size_t g4 = base4 + r * 512 + tid;
            const float4 v = *(const float4*)(x + g4 * 4);
            ushort4 o;
            o.x = f2bf_rne(v.x);
            o.y = f2bf_rne(v.y);
            o.z = f2bf_rne(v.z);
            o.w = f2bf_rne(v.w);
            *(ushort4*)(A2 + g4 * 4) = o;
        }
        return;
    }

    // ---------------- build role ----------------
    const int j0 = blockIdx.x * 2;

#pragma unroll
    for (int v = 0; v < 2; ++v)
#pragma unroll
        for (int e = 0; e < 2; ++e) {
            const int idx = tid + e * TBW;
            buf[0][v][idx] = make_float2(idx == (j0 + v) ? 1.0f : 0.0f, 0.0f);
        }
    __syncthreads();

    int sb = 0;
    for (int d = 0; d < 2; ++d) {
        // ---- 9 perm passes, mirror-pair; index math shared across vectors ----
        for (int jp = 0; jp < 9; ++jp) {
            const int s = 4 << jp;
            const int h = s >> 1;
            const int hh = s >> 2;
            const float* lg = logits + (d * 9 + jp) * 3;
            const float p0 = 1.0f / (1.0f + expf(-lg[0]));
            const float p1 = 1.0f / (1.0f + expf(-lg[1]));
            const float p2 = 1.0f / (1.0f + expf(-lg[2]));

            // pair id is identical for both vectors (tau = tid, tid+512)
            const int pid = tid;                   // 0..511
            const int w = pid & ((s >> 1) - 1);    // pair within s-block
            const int base = (pid >> (jp + 1)) << (jp + 2);

            int t, tm;
            float psel;
            if (w < hh) { t = w;          tm = h - 1 - w;  psel = p1; }
            else        { const int u = w - hh; t = h + u; tm = s - 1 - u; psel = p2; }

            const int eot = (t  < h) ? (2 * t)  : (2 * (t  - h) + 1);
            const int eom = (tm < h) ? (2 * tm) : (2 * (tm - h) + 1);

#pragma unroll
            for (int v = 0; v < 2; ++v) {
                const float2* src = buf[sb][v];
                float2* dst = buf[sb ^ 1][v];

                const float2 xt = src[base + t],  xet = src[base + eot];
                const float2 xm = src[base + tm], xem = src[base + eom];
                float2 yt, ym;
                yt.x = xt.x + p0 * (xet.x - xt.x);
                yt.y = xt.y + p0 * (xet.y - xt.y);
                ym.x = xm.x + p0 * (xem.x - xm.x);
                ym.y = xm.y + p0 * (xem.y - xm.y);

                float2 ot, om;
                ot.x = yt.x + psel * (ym.x - yt.x);
                ot.y = yt.y + psel * (ym.y - yt.y);
                om.x = ym.x + psel * (yt.x - ym.x);
                om.y = ym.y + psel * (yt.y - ym.y);
                dst[base + t]  = ot;
                dst[base + tm] = om;
            }
            __syncthreads();
            sb ^= 1;
        }

        // ---- 10 butterfly passes with coefficient prefetch ----
        float2 dgc[2], sbc[2], spc[2];
        {
            // preload pass i=0 coefficients (k = 512)
            const float2* Dg  = (const float2*)(diags + (size_t)((d * 10) * N) * 2);
            const float2* Sbc = (const float2*)(subd  + (size_t)((d * 10) * N) * 2);
            const float2* Spc = (const float2*)(supd  + (size_t)((d * 10) * N) * 2);
            const int k = N >> 1;
#pragma unroll
            for (int e = 0; e < 2; ++e) {
                const int idx = tid + e * TBW;
                dgc[e] = Dg[idx];
                sbc[e] = (idx >= k)    ? Sbc[idx - k] : make_float2(0.f, 0.f);
                spc[e] = (idx < N - k) ? Spc[idx]     : make_float2(0.f, 0.f);
            }
        }
        for (int i = 0; i < 10; ++i) {
            const int k = N >> (i + 1);

            // prefetch pass i+1 coefficients (issued before this pass's LDS
            // reads; consumed after the barrier below)
            float2 dgn[2], sbn[2], spn[2];
            if (i < 9) {
                const float2* Dg  = (const float2*)(diags + (size_t)((d * 10 + i + 1) * N) * 2);
                const float2* Sbc = (const float2*)(subd  + (size_t)((d * 10 + i + 1) * N) * 2);
                const float2* Spc = (const float2*)(supd  + (size_t)((d * 10 + i + 1) * N) * 2);
                const int kn = N >> (i + 2);
#pragma unroll
                for (int e = 0; e < 2; ++e) {
                    const int idx = tid + e * TBW;
                    dgn[e] = Dg[idx];
                    sbn[e] = (idx >= kn)    ? Sbc[idx - kn] : make_float2(0.f, 0.f);
                    spn[e] = (idx < N - kn) ? Spc[idx]      : make_float2(0.f, 0.f);
                }
            }

#pragma unroll
            for (int e = 0; e < 2; ++e) {
                const int idx = tid + e * TBW;
#pragma unroll
                for (int v = 0; v < 2; ++v) {
                    const float2* src = buf[sb][v];
                    const float2 xv = src[idx];
                    float2 o;
                    o.x = dgc[e].x * xv.x - dgc[e].y * xv.y;
                    o.y = dgc[e].x * xv.y + dgc[e].y * xv.x;
                    if (idx >= k) {
                        const float2 xs = src[idx - k];
                        o.x += sbc[e].x * xs.x - sbc[e].y * xs.y;
                        o.y += sbc[e].x * xs.y + sbc[e].y * xs.x;
                    }
                    if (idx < N - k) {
                        const float2 xp = src[idx + k];
                        o.x += spc[e].x * xp.x - spc[e].y * xp.y;
                        o.y += spc[e].x * xp.y + spc[e].y * xp.x;
                    }
                    buf[sb ^ 1][v][idx] = o;
                }
            }
            __syncthreads();
            sb ^= 1;
            if (i < 9) {
#pragma unroll
                for (int e = 0; e < 2; ++e) {
                    dgc[e] = dgn[e];
                    sbc[e] = sbn[e];
                    spc[e] = spn[e];
                }
            }
        }
    }

    // ---- epilogue: scatter-write transposed bf16 directly: Bt[n][j0+v] ----
#pragma unroll
    for (int v = 0; v < 2; ++v)
#pragma unroll
        for (int e = 0; e < 2; ++e) {
            const int idx = tid + e * TBW;
            Bt[(size_t)idx * N + (j0 + v)] = f2bf_rne(buf[sb][v][idx].x);
        }
}

// ---------------------------------------------------------------------------
// GEMM: BM=64 x BN=64 tile, BK=64, grid (64,16)=1024 blocks -> 4 blocks/CU.
// m97-style 2-barrier single-buffer K-loop; XOR-swizzled LDS; unchanged
// from round 9 (known good).
// ---------------------------------------------------------------------------
typedef __attribute__((ext_vector_type(8))) __bf16 bf16x8;
typedef __attribute__((ext_vector_type(4))) float f32x4;

#define GLB(p) ((const __attribute__((address_space(1))) void*)(p))
#define LDS(p) ((__attribute__((address_space(3))) void*)(p))

__global__ __launch_bounds__(THREADS) void gemm_bf16(
    const unsigned short* __restrict__ A2,  // [B][1024] bf16
    const unsigned short* __restrict__ Bt,  // [1024][1024] bf16
    const float* __restrict__ bias,
    float* __restrict__ out)
{
    __shared__ __align__(16) unsigned short As[64 * 64];    // 8 KB
    __shared__ __align__(16) unsigned short Bs[64 * 64];    // 8 KB

    const int m0 = blockIdx.x * 64;
    const int n0 = blockIdx.y * 64;
    const int tid = threadIdx.x;
    const int wave = tid >> 6, lane = tid & 63;
    const int wm = (wave >> 1) * 32, wn = (wave & 1) * 32;
    const int lrow = lane & 15, q = lane >> 4;
    const int r7 = lrow & 7;

    f32x4 acc[2][2] = {};

    for (int kt = 0; kt < 16; ++kt) {
        const int k0 = kt * 64;
        __syncthreads();  // previous tile fully consumed
        {
            const unsigned short* gA = A2 + (size_t)m0 * N + k0;
            const unsigned short* gB = Bt + (size_t)n0 * N + k0;
#pragma unroll
            for (int r = 0; r < 2; ++r) {
                const int s = r * 256 + tid;
                const int row = s >> 3;
                const int gl = (s & 7) ^ (row & 7);  // XOR-swizzled k-group
                __builtin_amdgcn_global_load_lds(GLB(gA + (size_t)row * N + gl * 8),
                                                 LDS(As + s * 8), 16, 0, 0);
                __builtin_amdgcn_global_load_lds(GLB(gB + (size_t)row * N + gl * 8),
                                                 LDS(Bs + s * 8), 16, 0, 0);
            }
        }
        __syncthreads();  // DMA drained -> tile ready

#pragma unroll
        for (int kk = 0; kk < 64; kk += 32) {
            const int pg = ((kk >> 3) + q) ^ r7;  // physical (swizzled) group
            bf16x8 a[2], b[2];
#pragma unroll
            for (int mi = 0; mi < 2; ++mi)
                a[mi] = *(const bf16x8*)(As + (wm + mi * 16 + lrow) * 64 + pg * 8);
#pragma unroll
            for (int ni = 0; ni < 2; ++ni)
                b[ni] = *(const bf16x8*)(Bs + (wn + ni * 16 + lrow) * 64 + pg * 8);
#pragma unroll
            for (int mi = 0; mi < 2; ++mi)
#pragma unroll
                for (int ni = 0; ni < 2; ++ni)
                    acc[mi][ni] = __builtin_amdgcn_mfma_f32_16x16x32_bf16(
                        a[mi], b[ni], acc[mi][ni], 0, 0, 0);
        }
    }

    // epilogue: C/D layout col=lane&15, row=q*4+reg
#pragma unroll
    for (int ni = 0; ni < 2; ++ni) {
        const int col = n0 + wn + ni * 16 + lrow;
        const float bv = bias[col];
#pragma unroll
        for (int mi = 0; mi < 2; ++mi)
#pragma unroll
            for (int r = 0; r < 4; ++r) {
                const int row = m0 + wm + mi * 16 + q * 4 + r;
                out[(size_t)row * N + col] = acc[mi][ni][r] + bv;
            }
    }
}

// ---------------------------------------------------------------------------
extern "C" void kernel_launch(void* const* d_in, const int* in_sizes, int n_in,
                              void* d_out, int out_size, void* d_ws, size_t ws_size,
                              hipStream_t stream) {
    const float* x      = (const float*)d_in[0];
    const float* logits = (const float*)d_in[1];
    const float* diags  = (const float*)d_in[2];
    const float* subd   = (const float*)d_in[3];
    const float* supd   = (const float*)d_in[4];
    const float* bias   = (const float*)d_in[5];
    float* out = (float*)d_out;

    const int B = in_sizes[0] / N;  // 4096

    const size_t off_Bt = 0;                                // Bt: 1024*1024*2 B
    const size_t off_A2 = 2u * 1024 * 1024;
    const size_t need   = off_A2 + (size_t)B * N * 2;       // A2: B*1024*2 B

    if (ws_size >= need && B == 4096) {
        unsigned short* Bt = (unsigned short*)((char*)d_ws + off_Bt);
        unsigned short* A2 = (unsigned short*)((char*)d_ws + off_A2);

        prep_kernel<<<dim3(NB_BUILD + 256), dim3(TBW), 0, stream>>>(
            logits, diags, subd, supd, x, Bt, A2);
        gemm_bf16<<<dim3(B / 64, 16), dim3(THREADS), 0, stream>>>(A2, Bt, bias, out);
    } else {
        trifat_kernel<<<dim3(B), dim3(THREADS), 0, stream>>>(
            x, logits, diags, subd, supd, bias, out, B);
    }
}

// Round 13
// 124.989 us; speedup vs baseline: 1.2437x; 1.0372x over previous
//
#include <hip/hip_runtime.h>

#define N 1024
#define THREADS 256
#define EPT 4  // fallback path

// ---------------------------------------------------------------------------
// Shared pass pipeline (fallback path only, known correct).
// ---------------------------------------------------------------------------
__device__ __forceinline__ float2* run_pipeline(
    float2* bufA, float2* bufB, int tid,
    const float* __restrict__ logits,
    const float* __restrict__ diags,
    const float* __restrict__ subd,
    const float* __restrict__ supd)
{
    float2* src = bufA;
    float2* dst = bufB;

    for (int d = 0; d < 2; ++d) {
        for (int j = 0; j < 9; ++j) {
            const int s = 4 << j;
            const int h = s >> 1;
            const float* lg = logits + (d * 9 + j) * 3;
            const float p0 = 1.0f / (1.0f + expf(-lg[0]));
            const float p1 = 1.0f / (1.0f + expf(-lg[1]));
            const float p2 = 1.0f / (1.0f + expf(-lg[2]));
#pragma unroll
            for (int e = 0; e < EPT; ++e) {
                const int idx = tid + e * THREADS;
                const int base = idx & ~(s - 1);
                const int t = idx & (s - 1);
                const bool lo = (t < h);

                const int eo_t = lo ? (2 * t) : (2 * (t - h) + 1);
                const float2 xt  = src[idx];
                const float2 xeo = src[base + eo_t];
                float2 yt;
                yt.x = xt.x + p0 * (xeo.x - xt.x);
                yt.y = xt.y + p0 * (xeo.y - xt.y);

                const int tm = lo ? (h - 1 - t) : (s + h - 1 - t);
                const float psel = lo ? p1 : p2;
                const int eo_m = (tm < h) ? (2 * tm) : (2 * (tm - h) + 1);
                const float2 xm   = src[base + tm];
                const float2 xmeo = src[base + eo_m];
                float2 ym;
                ym.x = xm.x + p0 * (xmeo.x - xm.x);
                ym.y = xm.y + p0 * (xmeo.y - xm.y);

                float2 o;
                o.x = yt.x + psel * (ym.x - yt.x);
                o.y = yt.y + psel * (ym.y - yt.y);
                dst[idx] = o;
            }
            __syncthreads();
            float2* tmp = src; src = dst; dst = tmp;
        }
        for (int i = 0; i < 10; ++i) {
            const int k = N >> (i + 1);
            const float2* Dg = (const float2*)(diags + (size_t)((d * 10 + i) * N) * 2);
            const float2* Sb = (const float2*)(subd  + (size_t)((d * 10 + i) * N) * 2);
            const float2* Sp = (const float2*)(supd  + (size_t)((d * 10 + i) * N) * 2);
#pragma unroll
            for (int e = 0; e < EPT; ++e) {
                const int idx = tid + e * THREADS;
                const float2 xv = src[idx];
                const float2 dg = Dg[idx];
                float2 o;
                o.x = dg.x * xv.x - dg.y * xv.y;
                o.y = dg.x * xv.y + dg.y * xv.x;
                if (idx >= k) {
                    const float2 xs = src[idx - k];
                    const float2 sb = Sb[idx - k];
                    o.x += sb.x * xs.x - sb.y * xs.y;
                    o.y += sb.x * xs.y + sb.y * xs.x;
                }
                if (idx < N - k) {
                    const float2 xp = src[idx + k];
                    const float2 sp = Sp[idx];
                    o.x += sp.x * xp.x - sp.y * xp.y;
                    o.y += sp.x * xp.y + sp.y * xp.x;
                }
                dst[idx] = o;
            }
            __syncthreads();
            float2* tmp = src; src = dst; dst = tmp;
        }
    }
    return src;
}

// ---------------------------------------------------------------------------
// Fallback: direct per-row kernel (round-1, known correct).
// ---------------------------------------------------------------------------
__global__ __launch_bounds__(THREADS) void trifat_kernel(
    const float* __restrict__ x,
    const float* __restrict__ logits,
    const float* __restrict__ diags,
    const float* __restrict__ subd,
    const float* __restrict__ supd,
    const float* __restrict__ bias,
    float* __restrict__ out,
    int B)
{
    __shared__ float2 bufA[N];
    __shared__ float2 bufB[N];

    const int row = blockIdx.x;
    const int tid = threadIdx.x;
    if (row >= B) return;

    const float* xr = x + (size_t)row * N;
#pragma unroll
    for (int e = 0; e < EPT; ++e) {
        int idx = tid + e * THREADS;
        bufA[idx] = make_float2(xr[idx], 0.0f);
    }
    __syncthreads();

    float2* res = run_pipeline(bufA, bufB, tid, logits, diags, subd, supd);

    float* orow = out + (size_t)row * N;
#pragma unroll
    for (int e = 0; e < EPT; ++e) {
        int idx = tid + e * THREADS;
        orow[idx] = res[idx].x + bias[idx];
    }
}

// ---------------------------------------------------------------------------
// bf16 helper
// ---------------------------------------------------------------------------
__device__ __forceinline__ unsigned short f2bf_rne(float f) {
    unsigned int u = __float_as_uint(f);
    unsigned int r = u + 0x7fffu + ((u >> 16) & 1u);
    return (unsigned short)(r >> 16);
}

// ---------------------------------------------------------------------------
// Fused prep kernel — r12 base (TBW=512, V=2, 32 KB, coeff prefetch) plus:
//   * depth-0 perm sparsity: support of e_j stays inside its s-block, so
//     pass s runs s/2 pair-tasks in the active block only (both buffers
//     zero-initialized => skipped outputs provably already 0).
//   * paired butterflies: thread owns contiguous {2t,2t+1}; b128 LDS ops
//     (half the LDS instruction count) + float4 coefficient prefetch.
//  blocks [0,512):   build 2 basis-vector images -> scatter Bt bf16
//  blocks [512,768): conv x -> A2 bf16
// ---------------------------------------------------------------------------
#define TBW 512
#define NB_BUILD 512

__global__ __launch_bounds__(TBW) void prep_kernel(
    const float* __restrict__ logits,
    const float* __restrict__ diags,
    const float* __restrict__ subd,
    const float* __restrict__ supd,
    const float* __restrict__ x,
    unsigned short* __restrict__ Bt,   // [1024][1024] bf16, Bt[n][j]
    unsigned short* __restrict__ A2)   // [B][1024] bf16
{
    __shared__ __align__(16) float2 buf[2][2][N];  // [buffer][vector][pos], 32 KB

    const int tid = threadIdx.x;

    if (blockIdx.x >= NB_BUILD) {
        // ---------------- conv role ----------------
        const int cb = blockIdx.x - NB_BUILD;        // 0..255
        const size_t base4 = (size_t)cb * 4096;      // float4 index base
#pragma unroll
        for (int r = 0; r < 8; ++r) {
            const size_t g4 = base4 + r * 512 + tid;
            const float4 v = *(const float4*)(x + g4 * 4);
            ushort4 o;
            o.x = f2bf_rne(v.x);
            o.y = f2bf_rne(v.y);
            o.z = f2bf_rne(v.z);
            o.w = f2bf_rne(v.w);
            *(ushort4*)(A2 + g4 * 4) = o;
        }
        return;
    }

    // ---------------- build role ----------------
    const int j0 = blockIdx.x * 2;
    const int t = tid;

    // zero-init BOTH buffers (required by depth-0 sparse perms), then seed
#pragma unroll
    for (int b = 0; b < 2; ++b)
#pragma unroll
        for (int v = 0; v < 2; ++v)
#pragma unroll
            for (int e = 0; e < 2; ++e)
                buf[b][v][tid + e * TBW] = make_float2(0.0f, 0.0f);
    __syncthreads();
    if (tid < 2) buf[0][tid][j0 + tid] = make_float2(1.0f, 0.0f);
    __syncthreads();

    int sb = 0;
    for (int d = 0; d < 2; ++d) {
        // ---- 9 perm passes, mirror-pair; depth-0 uses sparse active block ----
        for (int jp = 0; jp < 9; ++jp) {
            const int s = 4 << jp;
            const int h = s >> 1;
            const int hh = s >> 2;
            const float* lg = logits + (d * 9 + jp) * 3;
            const float p0 = 1.0f / (1.0f + expf(-lg[0]));
            const float p1 = 1.0f / (1.0f + expf(-lg[1]));
            const float p2 = 1.0f / (1.0f + expf(-lg[2]));

            int w = -1, base = 0;
            if (d == 0) {
                // sparse: only the s-block containing j0 is nonzero
                if (tid < (s >> 1)) {
                    w = tid;
                    base = (j0 >> (jp + 2)) << (jp + 2);
                }
            } else {
                w = tid & ((s >> 1) - 1);
                base = (tid >> (jp + 1)) << (jp + 2);
            }

            if (w >= 0) {
                int tt, tm;
                float psel;
                if (w < hh) { tt = w;         tm = h - 1 - w;  psel = p1; }
                else        { const int u = w - hh; tt = h + u; tm = s - 1 - u; psel = p2; }

                const int eot = (tt < h) ? (2 * tt) : (2 * (tt - h) + 1);
                const int eom = (tm < h) ? (2 * tm) : (2 * (tm - h) + 1);

#pragma unroll
                for (int v = 0; v < 2; ++v) {
                    const float2* src = buf[sb][v];
                    float2* dst = buf[sb ^ 1][v];

                    const float2 xt = src[base + tt], xet = src[base + eot];
                    const float2 xm = src[base + tm], xem = src[base + eom];
                    float2 yt, ym;
                    yt.x = xt.x + p0 * (xet.x - xt.x);
                    yt.y = xt.y + p0 * (xet.y - xt.y);
                    ym.x = xm.x + p0 * (xem.x - xm.x);
                    ym.y = xm.y + p0 * (xem.y - xm.y);

                    float2 ot, om;
                    ot.x = yt.x + psel * (ym.x - yt.x);
                    ot.y = yt.y + psel * (ym.y - yt.y);
                    om.x = ym.x + psel * (yt.x - ym.x);
                    om.y = ym.y + psel * (yt.y - ym.y);
                    dst[base + tt] = ot;
                    dst[base + tm] = om;
                }
            }
            __syncthreads();
            sb ^= 1;
        }

        // ---- butterfly passes: 9 paired (k even) + 1 scalar (k=1) ----
        float4 dg4, sb4, sp4;
        {   // preload pass i=0 (k=512, k2=256)
            const float4* Dg4 = (const float4*)(diags + (size_t)((d * 10) * N) * 2);
            const float4* Sb4 = (const float4*)(subd  + (size_t)((d * 10) * N) * 2);
            const float4* Sp4 = (const float4*)(supd  + (size_t)((d * 10) * N) * 2);
            dg4 = Dg4[t];
            sb4 = (t >= 256) ? Sb4[t - 256] : make_float4(0.f, 0.f, 0.f, 0.f);
            sp4 = (t < 256)  ? Sp4[t]       : make_float4(0.f, 0.f, 0.f, 0.f);
        }
        for (int i = 0; i < 9; ++i) {
            const int k = N >> (i + 1);
            const int k2 = k >> 1;

            // prefetch pass i+1 (paired) — issued before LDS reads
            float4 dg4n, sb4n, sp4n;
            if (i < 8) {
                const int kn2 = k2 >> 1;
                const float4* Dg4 = (const float4*)(diags + (size_t)((d * 10 + i + 1) * N) * 2);
                const float4* Sb4 = (const float4*)(subd  + (size_t)((d * 10 + i + 1) * N) * 2);
                const float4* Sp4 = (const float4*)(supd  + (size_t)((d * 10 + i + 1) * N) * 2);
                dg4n = Dg4[t];
                sb4n = (t >= kn2)       ? Sb4[t - kn2] : make_float4(0.f, 0.f, 0.f, 0.f);
                sp4n = (t < 512 - kn2)  ? Sp4[t]       : make_float4(0.f, 0.f, 0.f, 0.f);
            }

            const bool has_sb = (t >= k2);
            const bool has_sp = (t < 512 - k2);
#pragma unroll
            for (int v = 0; v < 2; ++v) {
                const float2* src = buf[sb][v];
                const float4 xv = *(const float4*)(&src[2 * t]);
                float4 o;
                o.x = dg4.x * xv.x - dg4.y * xv.y;
                o.y = dg4.x * xv.y + dg4.y * xv.x;
                o.z = dg4.z * xv.z - dg4.w * xv.w;
                o.w = dg4.z * xv.w + dg4.w * xv.z;
                if (has_sb) {
                    const float4 xs = *(const float4*)(&src[2 * t - k]);
                    o.x += sb4.x * xs.x - sb4.y * xs.y;
                    o.y += sb4.x * xs.y + sb4.y * xs.x;
                    o.z += sb4.z * xs.z - sb4.w * xs.w;
                    o.w += sb4.z * xs.w + sb4.w * xs.z;
                }
                if (has_sp) {
                    const float4 xp = *(const float4*)(&src[2 * t + k]);
                    o.x += sp4.x * xp.x - sp4.y * xp.y;
                    o.y += sp4.x * xp.y + sp4.y * xp.x;
                    o.z += sp4.z * xp.z - sp4.w * xp.w;
                    o.w += sp4.z * xp.w + sp4.w * xp.z;
                }
                *(float4*)(&buf[sb ^ 1][v][2 * t]) = o;
            }
            __syncthreads();
            sb ^= 1;
            if (i < 8) { dg4 = dg4n; sb4 = sb4n; sp4 = sp4n; }
        }
        {   // k = 1 scalar pass
            const float2* Dg = (const float2*)(diags + (size_t)((d * 10 + 9) * N) * 2);
            const float2* Sb = (const float2*)(subd  + (size_t)((d * 10 + 9) * N) * 2);
            const float2* Sp = (const float2*)(supd  + (size_t)((d * 10 + 9) * N) * 2);
            const int i0 = 2 * t, i1 = 2 * t + 1;
            const float2 dg0 = Dg[i0], dg1 = Dg[i1];
            const float2 sb0 = (t >= 1) ? Sb[i0 - 1] : make_float2(0.f, 0.f);
            const float2 sb1 = Sb[i0];
            const float2 sp0 = Sp[i0];
            const float2 sp1 = (t < 511) ? Sp[i1] : make_float2(0.f, 0.f);
#pragma unroll
            for (int v = 0; v < 2; ++v) {
                const float2* src = buf[sb][v];
                const float2 x0 = src[i0], x1 = src[i1];
                float2 o0, o1;
                o0.x = dg0.x * x0.x - dg0.y * x0.y;
                o0.y = dg0.x * x0.y + dg0.y * x0.x;
                o1.x = dg1.x * x1.x - dg1.y * x1.y;
                o1.y = dg1.x * x1.y + dg1.y * x1.x;
                if (t >= 1) {
                    const float2 xs = src[i0 - 1];
                    o0.x += sb0.x * xs.x - sb0.y * xs.y;
                    o0.y += sb0.x * xs.y + sb0.y * xs.x;
                }
                // i1 >= 1 always: sub term for o1 uses src[i0] = x0
                o1.x += sb1.x * x0.x - sb1.y * x0.y;
                o1.y += sb1.x * x0.y + sb1.y * x0.x;
                // i0 < 1023 always: sup term for o0 uses src[i1] = x1
                o0.x += sp0.x * x1.x - sp0.y * x1.y;
                o0.y += sp0.x * x1.y + sp0.y * x1.x;
                if (t < 511) {
                    const float2 xp = src[i1 + 1];
                    o1.x += sp1.x * xp.x - sp1.y * xp.y;
                    o1.y += sp1.x * xp.y + sp1.y * xp.x;
                }
                float4 ow;
                ow.x = o0.x; ow.y = o0.y; ow.z = o1.x; ow.w = o1.y;
                *(float4*)(&buf[sb ^ 1][v][i0]) = ow;
            }
            __syncthreads();
            sb ^= 1;
        }
    }

    // ---- epilogue: scatter-write transposed bf16 directly: Bt[n][j0+v] ----
#pragma unroll
    for (int v = 0; v < 2; ++v)
#pragma unroll
        for (int e = 0; e < 2; ++e) {
            const int idx = tid + e * TBW;
            Bt[(size_t)idx * N + (j0 + v)] = f2bf_rne(buf[sb][v][idx].x);
        }
}

// ---------------------------------------------------------------------------
// GEMM: BM=64 x BN=64 tile, BK=64, grid (64,16)=1024 blocks -> 4 blocks/CU.
// m97-style 2-barrier single-buffer K-loop; XOR-swizzled LDS; unchanged
// from round 9 (known good).
// ---------------------------------------------------------------------------
typedef __attribute__((ext_vector_type(8))) __bf16 bf16x8;
typedef __attribute__((ext_vector_type(4))) float f32x4;

#define GLB(p) ((const __attribute__((address_space(1))) void*)(p))
#define LDS(p) ((__attribute__((address_space(3))) void*)(p))

__global__ __launch_bounds__(THREADS) void gemm_bf16(
    const unsigned short* __restrict__ A2,  // [B][1024] bf16
    const unsigned short* __restrict__ Bt,  // [1024][1024] bf16
    const float* __restrict__ bias,
    float* __restrict__ out)
{
    __shared__ __align__(16) unsigned short As[64 * 64];    // 8 KB
    __shared__ __align__(16) unsigned short Bs[64 * 64];    // 8 KB

    const int m0 = blockIdx.x * 64;
    const int n0 = blockIdx.y * 64;
    const int tid = threadIdx.x;
    const int wave = tid >> 6, lane = tid & 63;
    const int wm = (wave >> 1) * 32, wn = (wave & 1) * 32;
    const int lrow = lane & 15, q = lane >> 4;
    const int r7 = lrow & 7;

    f32x4 acc[2][2] = {};

    for (int kt = 0; kt < 16; ++kt) {
        const int k0 = kt * 64;
        __syncthreads();  // previous tile fully consumed
        {
            const unsigned short* gA = A2 + (size_t)m0 * N + k0;
            const unsigned short* gB = Bt + (size_t)n0 * N + k0;
#pragma unroll
            for (int r = 0; r < 2; ++r) {
                const int s = r * 256 + tid;
                const int row = s >> 3;
                const int gl = (s & 7) ^ (row & 7);  // XOR-swizzled k-group
                __builtin_amdgcn_global_load_lds(GLB(gA + (size_t)row * N + gl * 8),
                                                 LDS(As + s * 8), 16, 0, 0);
                __builtin_amdgcn_global_load_lds(GLB(gB + (size_t)row * N + gl * 8),
                                                 LDS(Bs + s * 8), 16, 0, 0);
            }
        }
        __syncthreads();  // DMA drained -> tile ready

#pragma unroll
        for (int kk = 0; kk < 64; kk += 32) {
            const int pg = ((kk >> 3) + q) ^ r7;  // physical (swizzled) group
            bf16x8 a[2], b[2];
#pragma unroll
            for (int mi = 0; mi < 2; ++mi)
                a[mi] = *(const bf16x8*)(As + (wm + mi * 16 + lrow) * 64 + pg * 8);
#pragma unroll
            for (int ni = 0; ni < 2; ++ni)
                b[ni] = *(const bf16x8*)(Bs + (wn + ni * 16 + lrow) * 64 + pg * 8);
#pragma unroll
            for (int mi = 0; mi < 2; ++mi)
#pragma unroll
                for (int ni = 0; ni < 2; ++ni)
                    acc[mi][ni] = __builtin_amdgcn_mfma_f32_16x16x32_bf16(
                        a[mi], b[ni], acc[mi][ni], 0, 0, 0);
        }
    }

    // epilogue: C/D layout col=lane&15, row=q*4+reg
#pragma unroll
    for (int ni = 0; ni < 2; ++ni) {
        const int col = n0 + wn + ni * 16 + lrow;
        const float bv = bias[col];
#pragma unroll
        for (int mi = 0; mi < 2; ++mi)
#pragma unroll
            for (int r = 0; r < 4; ++r) {
                const int row = m0 + wm + mi * 16 + q * 4 + r;
                out[(size_t)row * N + col] = acc[mi][ni][r] + bv;
            }
    }
}

// ---------------------------------------------------------------------------
extern "C" void kernel_launch(void* const* d_in, const int* in_sizes, int n_in,
                              void* d_out, int out_size, void* d_ws, size_t ws_size,
                              hipStream_t stream) {
    const float* x      = (const float*)d_in[0];
    const float* logits = (const float*)d_in[1];
    const float* diags  = (const float*)d_in[2];
    const float* subd   = (const float*)d_in[3];
    const float* supd   = (const float*)d_in[4];
    const float* bias   = (const float*)d_in[5];
    float* out = (float*)d_out;

    const int B = in_sizes[0] / N;  // 4096

    const size_t off_Bt = 0;                                // Bt: 1024*1024*2 B
    const size_t off_A2 = 2u * 1024 * 1024;
    const size_t need   = off_A2 + (size_t)B * N * 2;       // A2: B*1024*2 B

    if (ws_size >= need && B == 4096) {
        unsigned short* Bt = (unsigned short*)((char*)d_ws + off_Bt);
        unsigned short* A2 = (unsigned short*)((char*)d_ws + off_A2);

        prep_kernel<<<dim3(NB_BUILD + 256), dim3(TBW), 0, stream>>>(
            logits, diags, subd, supd, x, Bt, A2);
        gemm_bf16<<<dim3(B / 64, 16), dim3(THREADS), 0, stream>>>(A2, Bt, bias, out);
    } else {
        trifat_kernel<<<dim3(B), dim3(THREADS), 0, stream>>>(
            x, logits, diags, subd, supd, bias, out, B);
    }
}